// Round 26
// baseline (154.578 us; speedup 1.0000x reference)
//
#include <hip/hip_runtime.h>

typedef unsigned short u16;
typedef unsigned int   u32;

typedef float  f32x4  __attribute__((ext_vector_type(4)));
typedef __bf16 bf16x8 __attribute__((ext_vector_type(8)));

#define S_LEN  4096
#define DMODEL 1024
#define NSUB   4
#define DSUB   256
#define HFF    512
#define NTOK   16384   // B*S = 4*4096

static_assert(sizeof(bf16x8) == 16, "frag size");

__device__ __forceinline__ u16 f2bf(float f) {
    union { float f; u32 u; } v; v.f = f;
    u32 r = (v.u + 0x7fffu + ((v.u >> 16) & 1u)) >> 16;   // RNE
    return (u16)r;
}

#define MFMA16(a, b, c) __builtin_amdgcn_mfma_f32_16x16x32_bf16((a), (b), (c), 0, 0, 0)

// async global->LDS, 16B per lane: per-lane global src, wave-uniform LDS base
__device__ __forceinline__ void gl_lds16(const void* g, void* l) {
    __builtin_amdgcn_global_load_lds(
        (const __attribute__((address_space(1))) void*)g,
        (__attribute__((address_space(3))) void*)l,
        16, 0, 0);
}
#define LGKM0 asm volatile("s_waitcnt lgkmcnt(0)" ::: "memory")
#define SCHED0 __builtin_amdgcn_sched_barrier(0)
#define SBAR __builtin_amdgcn_s_barrier()

// ---------------------- merged prep: weight repack + RMSNorm/RoPE
// blocks [0,1280): fragment-packed repack
//   dst[b][C/16][K/32][lane 64][8] = bf16(src[b][k][c]),
//   k = kt*32 + (lane>>4)*8 + j, c = ct*16 + (lane&15)
// blocks [1280, 1280+16384): norm+rope for token (bid-1280)
__global__ __launch_bounds__(256) void k_prep(const float* __restrict__ Wg,
                                              const float* __restrict__ Wu,
                                              const float* __restrict__ Wd,
                                              const float* __restrict__ Wo,
                                              const float* __restrict__ x,
                                              const float* __restrict__ nw,
                                              u16* __restrict__ wgP,
                                              u16* __restrict__ wuP,
                                              u16* __restrict__ wdP,
                                              u16* __restrict__ woP,
                                              u16* __restrict__ h) {
    int bid = blockIdx.x;
    int tid = threadIdx.x;
    if (bid < 1280) {
        __shared__ float tl[32][65];
        const float* src; u16* dst; int K, C, rel;
        if (bid < 256)      { src = Wg; dst = wgP; K = 256;  C = 512;  rel = bid; }
        else if (bid < 512) { src = Wu; dst = wuP; K = 256;  C = 512;  rel = bid - 256; }
        else if (bid < 768) { src = Wd; dst = wdP; K = 512;  C = 256;  rel = bid - 512; }
        else                { src = Wo; dst = woP; K = 1024; C = 1024; rel = bid - 768; }
        int ncb = C >> 6, nkt = K >> 5;
        int cb = rel % ncb; int r2 = rel / ncb;
        int kt = r2 % nkt;  int b  = r2 / nkt;
        {
            int r = tid >> 3, c0 = (tid & 7) * 8;
            const float* s = src + ((size_t)(b * K + kt * 32 + r)) * C + cb * 64 + c0;
            float4 v0 = *(const float4*)(s);
            float4 v1 = *(const float4*)(s + 4);
            tl[r][c0 + 0] = v0.x; tl[r][c0 + 1] = v0.y; tl[r][c0 + 2] = v0.z; tl[r][c0 + 3] = v0.w;
            tl[r][c0 + 4] = v1.x; tl[r][c0 + 5] = v1.y; tl[r][c0 + 6] = v1.z; tl[r][c0 + 7] = v1.w;
        }
        __syncthreads();
        {
            int f = tid >> 6, l = tid & 63;
            union { u16 v[8]; uint4 q; } u;
#pragma unroll
            for (int j = 0; j < 8; ++j)
                u.v[j] = f2bf(tl[(l >> 4) * 8 + j][f * 16 + (l & 15)]);
            size_t ctile = (size_t)(b * (C >> 4) + cb * 4 + f);
            *(uint4*)(dst + (ctile * nkt + kt) * 512 + l * 8) = u.q;
        }
        return;
    }
    // ---- norm + rope
    int tok = bid - 1280;
    int s = tok & (S_LEN - 1);
    int t = tid;
    const float* xr = x + (size_t)tok * DMODEL;
    float x0 = xr[t], x1 = xr[t + 256], x2 = xr[t + 512], x3 = xr[t + 768];
    float ss = x0 * x0 + x1 * x1 + x2 * x2 + x3 * x3;
#pragma unroll
    for (int o = 32; o > 0; o >>= 1) ss += __shfl_down(ss, o, 64);
    __shared__ float red[4];
    if ((t & 63) == 0) red[t >> 6] = ss;
    __syncthreads();
    float tot = red[0] + red[1] + red[2] + red[3];
    float sc = rsqrtf(tot * (1.0f / DMODEL) + 1e-6f);
    float n0 = x0 * sc * nw[t];
    float n1 = x1 * sc * nw[t + 256];
    float n2 = x2 * sc * nw[t + 512];
    float n3 = x3 * sc * nw[t + 768];
    const float C = -0.017988946039015984f;   // -ln(10000)/512
    float sf = (float)s;
    float ang0 = sf * expf(C * (float)t);
    float ang1 = sf * expf(C * (float)(t + 256));
    float sn0, cs0, sn1, cs1;
    sincosf(ang0, &sn0, &cs0);
    sincosf(ang1, &sn1, &cs1);
    u16* hr = h + (size_t)tok * DMODEL;
    hr[t]       = f2bf(n0 * cs0 - n2 * sn0);
    hr[t + 256] = f2bf(n1 * cs1 - n3 * sn1);
    hr[t + 512] = f2bf(n2 * cs0 + n0 * sn0);
    hr[t + 768] = f2bf(n3 * cs1 + n1 * sn1);
}

// ---------------------------------------------------------- grouped SwiGLU
// R25 (76.6us) + ISSUE DISTANCE 3->2: ISSUE(t+2) writes slot (t+2)%3 which
// never collides with the slot being read (t%3) or the in-flight (t+1)%3 —
// so the per-stage hard LGKM0+SCHED0 drain (~120cy serial LDS round-trip,
// 24x/block) is DELETED; compiler emits fine-grained lgkmcnt for the
// weight-read->MFMA deps. Steady vmcnt(4) (one 4-load stage in flight).
// Prefetch cover 2 stages (~620cy) >> L2 latency. LDS 160KB, 4 barriers.
__global__ __launch_bounds__(512, 1)
void k_swiglu(const u16* __restrict__ h,
              const u16* __restrict__ wgP,   // [4][32][8][64][8]
              const u16* __restrict__ wuP,   // [4][32][8][64][8]
              const u16* __restrict__ wdP,   // [4][16][16][64][8]
              u16* __restrict__ dmid) {
    int bid = blockIdx.x;
    int mb = bid & 255, n = bid >> 8;
    int m0 = mb * 64;
    int tid = threadIdx.x;
    int lane = tid & 63, wid = tid >> 6;

    __shared__ u16 hA[64 * 256];          // 32KB, swizzled
    __shared__ u16 sT[2][64 * 128];       // 2 x 16KB, swizzled
    __shared__ u16 sW[8 * 3 * 2048];      // 96KB [wave][ring3][4 slots x 512]

    const u16* wg = wgP + (size_t)n * (32 * 8 * 512);
    const u16* wu = wuP + (size_t)n * (32 * 8 * 512);
    const u16* wd = wdP + (size_t)n * (16 * 16 * 512);
    u16* myW = sW + wid * 6144;

    // stage t (0..23): hc=t/6, r=t%6; r<4 -> gu ks={2r,2r+1};
    // r in {4,5} -> down k2={2(r-4), 2(r-4)+1}
#define ISSUE(t)                                                               \
    do {                                                                       \
        if ((t) < 24) {                                                        \
            const int hcs = (t) / 6, rs = (t) % 6;                             \
            u16* db = myW + ((t) % 3) * 2048;                                  \
            if (rs < 4) {                                                      \
                size_t ct0 = (size_t)(hcs * 8 + wid);                          \
                const int ks0 = rs * 2;                                        \
                gl_lds16(wg + (ct0 * 8 + ks0) * 512 + lane * 8, db);           \
                gl_lds16(wu + (ct0 * 8 + ks0) * 512 + lane * 8, db + 512);     \
                gl_lds16(wg + (ct0 * 8 + ks0 + 1) * 512 + lane * 8, db + 1024);\
                gl_lds16(wu + (ct0 * 8 + ks0 + 1) * 512 + lane * 8, db + 1536);\
            } else {                                                           \
                const int k20 = (rs - 4) * 2;                                  \
                gl_lds16(wd + ((size_t)(wid * 2 + 0) * 16 + hcs * 4 + k20) * 512 + lane * 8, db);            \
                gl_lds16(wd + ((size_t)(wid * 2 + 1) * 16 + hcs * 4 + k20) * 512 + lane * 8, db + 512);      \
                gl_lds16(wd + ((size_t)(wid * 2 + 0) * 16 + hcs * 4 + k20 + 1) * 512 + lane * 8, db + 1024); \
                gl_lds16(wd + ((size_t)(wid * 2 + 1) * 16 + hcs * 4 + k20 + 1) * 512 + lane * 8, db + 1536); \
            }                                                                  \
        }                                                                      \
    } while (0)
    // wait until stage t's 4 loads landed (stage t+1's 4 may be in flight)
#define VMW(t)                                                                 \
    do {                                                                       \
        if ((t) <= 22) asm volatile("s_waitcnt vmcnt(4)" ::: "memory");        \
        else           asm volatile("s_waitcnt vmcnt(0)" ::: "memory");        \
    } while (0)

    // ---- prologue: h tile -> regs (oldest vmem), ring 0..1, then hA
    const u16* hbase = h + (size_t)m0 * DMODEL + n * DSUB;
    uint4 hv[4];
#pragma unroll
    for (int it = 0; it < 4; ++it) {
        int e = (tid + it * 512) * 8;
        int r = e >> 8, c = e & 255;
        hv[it] = *(const uint4*)(hbase + (size_t)r * DMODEL + c);
    }
    ISSUE(0); ISSUE(1);
#pragma unroll
    for (int it = 0; it < 4; ++it) {
        int e = (tid + it * 512) * 8;
        int r = e >> 8, c = e & 255;
        u32 off = ((u32)(r * 512 + c * 2)) ^ ((u32)(r & 7) << 4);
        *(uint4*)((char*)hA + off) = hv[it];
    }
    LGKM0; SBAR;

    const f32x4 zero = {0.f, 0.f, 0.f, 0.f};
    f32x4 accd[4][2];
#pragma unroll
    for (int a = 0; a < 4; ++a) { accd[a][0] = zero; accd[a][1] = zero; }

#pragma unroll
    for (int hc = 0; hc < 4; ++hc) {
        // ======== gate/up: 4 wide stages (2 K-steps each)
        f32x4 accg[4], accu[4];
#pragma unroll
        for (int a = 0; a < 4; ++a) { accg[a] = zero; accu[a] = zero; }

#pragma unroll
        for (int ks2 = 0; ks2 < 4; ++ks2) {
            const int t = hc * 6 + ks2;
            VMW(t); SCHED0;
            const u16* rb = myW + (t % 3) * 2048;
            bf16x8 bg0 = *(const bf16x8*)(rb + lane * 8);
            bf16x8 bu0 = *(const bf16x8*)(rb + 512 + lane * 8);
            bf16x8 bg1 = *(const bf16x8*)(rb + 1024 + lane * 8);
            bf16x8 bu1 = *(const bf16x8*)(rb + 1536 + lane * 8);
            ISSUE(t + 2);             // writes slot (t+2)%3 != t%3: no drain
            __builtin_amdgcn_s_setprio(1);
#pragma unroll
            for (int half = 0; half < 2; ++half) {
                const int ks = ks2 * 2 + half;
#pragma unroll
                for (int rt = 0; rt < 4; ++rt) {
                    int arow = rt * 16 + (lane & 15);
                    int k0 = ks * 32 + (lane >> 4) * 8;
                    u32 off = ((u32)(arow * 512 + k0 * 2)) ^ ((u32)(arow & 7) << 4);
                    bf16x8 afr = *(const bf16x8*)((const char*)hA + off);
                    accg[rt] = MFMA16(afr, half ? bg1 : bg0, accg[rt]);
                    accu[rt] = MFMA16(afr, half ? bu1 : bu0, accu[rt]);
                }
            }
            __builtin_amdgcn_s_setprio(0);
        }

        // ======== t = silu(g)*u -> sT[hc&1] (swizzled scatter); rcp silu
        u16* sTc = (u16*)sT[hc & 1];
#pragma unroll
        for (int rt = 0; rt < 4; ++rt) {
            int rbase = rt * 16 + (lane >> 4) * 4;
            int col = wid * 16 + (lane & 15);
#pragma unroll
            for (int q = 0; q < 4; ++q) {
                float g = accg[rt][q], u = accu[rt][q];
                float tv = g * u * __builtin_amdgcn_rcpf(1.0f + __expf(-g));
                int row = rbase + q;
                u32 off = ((u32)(row * 256 + col * 2)) ^ ((u32)(row & 7) << 4);
                *(u16*)((char*)sTc + off) = f2bf(tv);
            }
        }
        LGKM0; SBAR;                  // publish sT[hc&1]; ring stays in flight

        // ======== down: 2 wide stages (2 K-steps each)
#pragma unroll
        for (int k22 = 0; k22 < 2; ++k22) {
            const int t = hc * 6 + 4 + k22;
            VMW(t); SCHED0;
            const u16* rb = myW + (t % 3) * 2048;
            bf16x8 bdA0 = *(const bf16x8*)(rb + lane * 8);
            bf16x8 bdB0 = *(const bf16x8*)(rb + 512 + lane * 8);
            bf16x8 bdA1 = *(const bf16x8*)(rb + 1024 + lane * 8);
            bf16x8 bdB1 = *(const bf16x8*)(rb + 1536 + lane * 8);
            ISSUE(t + 2);             // no drain needed (slot disjoint)
            __builtin_amdgcn_s_setprio(1);
#pragma unroll
            for (int half = 0; half < 2; ++half) {
                const int k2 = k22 * 2 + half;
#pragma unroll
                for (int rt = 0; rt < 4; ++rt) {
                    int arow = rt * 16 + (lane & 15);
                    int k0 = k2 * 32 + (lane >> 4) * 8;
                    u32 off = ((u32)(arow * 256 + k0 * 2)) ^ ((u32)(arow & 7) << 4);
                    bf16x8 afr = *(const bf16x8*)((const char*)sTc + off);
                    accd[rt][0] = MFMA16(afr, half ? bdA1 : bdA0, accd[rt][0]);
                    accd[rt][1] = MFMA16(afr, half ? bdB1 : bdB0, accd[rt][1]);
                }
            }
            __builtin_amdgcn_s_setprio(0);
        }
        // no barrier: next silu writes sT[(hc+1)&1]; all readers of that
        // buffer (down(hc-1)) completed before the silu(hc) barrier above
    }
#undef ISSUE
#undef VMW

    // ---- write dmid [64][256] n-slice as bf16
#pragma unroll
    for (int rt = 0; rt < 4; ++rt)
#pragma unroll
        for (int ct = 0; ct < 2; ++ct) {
            int rbase = m0 + rt * 16 + (lane >> 4) * 4;
            int col = n * DSUB + wid * 32 + ct * 16 + (lane & 15);
#pragma unroll
            for (int q = 0; q < 4; ++q)
                dmid[(size_t)(rbase + q) * DMODEL + col] = f2bf(accd[rt][ct][q]);
        }
}

// -------------------------------------------------- final GEMM + residual
// R8 loop structure + residual-init (best measured ~27-34us): acc loaded
// from x in the PROLOGUE (overlaps chunk-0 staging), store-only epilogue.
__global__ __launch_bounds__(512, 2) void k_final(const u16* __restrict__ dmid,
                                                  const u16* __restrict__ woP,   // [64][32][64][8]
                                                  const float* __restrict__ x,
                                                  float* __restrict__ out) {
    int bid = blockIdx.x;
    int mb = bid & 127, nb = bid >> 7;
    int m0 = mb * 128, n0 = nb * 256;
    int tid = threadIdx.x;
    int lane = tid & 63, wid = tid >> 6;
    int wr = wid >> 2, wc = wid & 3;

    __shared__ u16 sA[2][128 * 256];     // 2 x 64KB, swizzled

    f32x4 acc[4][4];
    const u16* dbase = dmid + (size_t)m0 * DMODEL;

    uint4 stA[8], stB[8];
    // chunk 0 -> stA, write sA[0]
#pragma unroll
    for (int it = 0; it < 8; ++it) {
        int e = (tid + it * 512) * 8;
        int r = e >> 8, c = e & 255;
        stA[it] = *(const uint4*)(dbase + (size_t)r * DMODEL + c);
    }
    // init acc from residual x (read overlaps staging; epilogue = store only)
#pragma unroll
    for (int rt = 0; rt < 4; ++rt)
#pragma unroll
        for (int ct = 0; ct < 4; ++ct) {
            int rbase = m0 + wr * 64 + rt * 16 + (lane >> 4) * 4;
            int col = n0 + wc * 64 + ct * 16 + (lane & 15);
#pragma unroll
            for (int q = 0; q < 4; ++q)
                acc[rt][ct][q] = x[(size_t)(rbase + q) * DMODEL + col];
        }
#pragma unroll
    for (int it = 0; it < 8; ++it) {
        int e = (tid + it * 512) * 8;
        int r = e >> 8, c = e & 255;
        u32 off = ((u32)(r * 512 + c * 2)) ^ ((u32)(r & 7) << 4);
        *(uint4*)((char*)sA[0] + off) = stA[it];
    }
    // issue chunk 1 -> stB
#pragma unroll
    for (int it = 0; it < 8; ++it) {
        int e = (tid + it * 512) * 8;
        int r = e >> 8, c = e & 255;
        stB[it] = *(const uint4*)(dbase + (size_t)r * DMODEL + 256 + c);
    }

#pragma unroll
    for (int kc = 0; kc < 4; ++kc) {
        __syncthreads();                       // sA[kc&1] ready
        if (kc < 3) {                          // write chunk kc+1 into sA[(kc+1)&1]
#pragma unroll
            for (int it = 0; it < 8; ++it) {
                int e = (tid + it * 512) * 8;
                int r = e >> 8, c = e & 255;
                u32 off = ((u32)(r * 512 + c * 2)) ^ ((u32)(r & 7) << 4);
                uint4 v = (kc & 1) ? stA[it] : stB[it];
                *(uint4*)((char*)sA[(kc + 1) & 1] + off) = v;
            }
        }
        if (kc < 2) {                          // issue chunk kc+2
#pragma unroll
            for (int it = 0; it < 8; ++it) {
                int e = (tid + it * 512) * 8;
                int r = e >> 8, c = e & 255;
                uint4 v = *(const uint4*)(dbase + (size_t)r * DMODEL + (kc + 2) * 256 + c);
                if ((kc & 1) == 0) stA[it] = v; else stB[it] = v;
            }
        }

        const u16* sAc = (const u16*)sA[kc & 1];
        bf16x8 wf[2][4];
#pragma unroll
        for (int ct = 0; ct < 4; ++ct) {
            size_t ctile = (size_t)(nb * 16 + wc * 4 + ct);
            size_t ktile = (size_t)(kc * 8 + 0);
            wf[0][ct] = *(const bf16x8*)(woP + (ctile * 32 + ktile) * 512 + lane * 8);
        }
#pragma unroll
        for (int ks = 0; ks < 8; ++ks) {
            if (ks < 7) {
#pragma unroll
                for (int ct = 0; ct < 4; ++ct) {
                    size_t ctile = (size_t)(nb * 16 + wc * 4 + ct);
                    size_t ktile = (size_t)(kc * 8 + ks + 1);
                    wf[(ks + 1) & 1][ct] = *(const bf16x8*)(woP + (ctile * 32 + ktile) * 512 + lane * 8);
                }
            }
            bf16x8 afr[4];
#pragma unroll
            for (int rt = 0; rt < 4; ++rt) {
                int arow = wr * 64 + rt * 16 + (lane & 15);
                int k0 = ks * 32 + (lane >> 4) * 8;
                u32 off = ((u32)(arow * 512 + k0 * 2)) ^ ((u32)(arow & 7) << 4);
                afr[rt] = *(const bf16x8*)((const char*)sAc + off);
            }
#pragma unroll
            for (int ct = 0; ct < 4; ++ct)
#pragma unroll
                for (int rt = 0; rt < 4; ++rt)
                    acc[rt][ct] = MFMA16(afr[rt], wf[ks & 1][ct], acc[rt][ct]);
        }
    }

    // epilogue: store only (residual already folded into acc init)
#pragma unroll
    for (int rt = 0; rt < 4; ++rt)
#pragma unroll
        for (int ct = 0; ct < 4; ++ct) {
            int rbase = m0 + wr * 64 + rt * 16 + (lane >> 4) * 4;
            int col = n0 + wc * 64 + ct * 16 + (lane & 15);
#pragma unroll
            for (int q = 0; q < 4; ++q) {
                size_t o = (size_t)(rbase + q) * DMODEL + col;
                out[o] = acc[rt][ct][q];
            }
        }
}

// ---------------------------------------------------------------- launcher
extern "C" void kernel_launch(void* const* d_in, const int* in_sizes, int n_in,
                              void* d_out, int out_size, void* d_ws, size_t ws_size,
                              hipStream_t stream) {
    const float* x  = (const float*)d_in[0];
    const float* nw = (const float*)d_in[1];
    const float* Wg = (const float*)d_in[2];
    const float* Wu = (const float*)d_in[3];
    const float* Wd = (const float*)d_in[4];
    const float* Wo = (const float*)d_in[5];
    float* out = (float*)d_out;

    char* ws = (char*)d_ws;
    const size_t MB = 1u << 20;
    u16* h    = (u16*)(ws);             // 32 MB
    u16* wgP  = (u16*)(ws + 32 * MB);   //  1 MB
    u16* wuP  = (u16*)(ws + 33 * MB);   //  1 MB
    u16* wdP  = (u16*)(ws + 34 * MB);   //  1 MB
    u16* woP  = (u16*)(ws + 35 * MB);   //  2 MB
    u16* dmid = (u16*)(ws + 37 * MB);   // 32 MB  (end: 69 MB)

    k_prep<<<1280 + NTOK, 256, 0, stream>>>(Wg, Wu, Wd, Wo, x, nw,
                                            wgP, wuP, wdP, woP, h);
    k_swiglu<<<256 * NSUB, 512, 0, stream>>>(h, wgP, wuP, wdP, dmid);
    k_final<<<128 * 4, 512, 0, stream>>>(dmid, woP, x, out);
}

// Round 27
// 152.812 us; speedup vs baseline: 1.0116x; 1.0116x over previous
//
#include <hip/hip_runtime.h>

typedef unsigned short u16;
typedef unsigned int   u32;

typedef float  f32x4  __attribute__((ext_vector_type(4)));
typedef __bf16 bf16x8 __attribute__((ext_vector_type(8)));

#define S_LEN  4096
#define DMODEL 1024
#define NSUB   4
#define DSUB   256
#define HFF    512
#define NTOK   16384   // B*S = 4*4096

static_assert(sizeof(bf16x8) == 16, "frag size");

__device__ __forceinline__ u16 f2bf(float f) {
    union { float f; u32 u; } v; v.f = f;
    u32 r = (v.u + 0x7fffu + ((v.u >> 16) & 1u)) >> 16;   // RNE
    return (u16)r;
}

#define MFMA16(a, b, c) __builtin_amdgcn_mfma_f32_16x16x32_bf16((a), (b), (c), 0, 0, 0)

// async global->LDS, 16B per lane: per-lane global src, wave-uniform LDS base
__device__ __forceinline__ void gl_lds16(const void* g, void* l) {
    __builtin_amdgcn_global_load_lds(
        (const __attribute__((address_space(1))) void*)g,
        (__attribute__((address_space(3))) void*)l,
        16, 0, 0);
}
#define LGKM0 asm volatile("s_waitcnt lgkmcnt(0)" ::: "memory")
#define SCHED0 __builtin_amdgcn_sched_barrier(0)
#define SBAR __builtin_amdgcn_s_barrier()

// ---------------------- merged prep: weight repack + RMSNorm/RoPE
// blocks [0,1280): fragment-packed repack
//   dst[b][C/16][K/32][lane 64][8] = bf16(src[b][k][c]),
//   k = kt*32 + (lane>>4)*8 + j, c = ct*16 + (lane&15)
// blocks [1280, 1280+16384): norm+rope for token (bid-1280)
__global__ __launch_bounds__(256) void k_prep(const float* __restrict__ Wg,
                                              const float* __restrict__ Wu,
                                              const float* __restrict__ Wd,
                                              const float* __restrict__ Wo,
                                              const float* __restrict__ x,
                                              const float* __restrict__ nw,
                                              u16* __restrict__ wgP,
                                              u16* __restrict__ wuP,
                                              u16* __restrict__ wdP,
                                              u16* __restrict__ woP,
                                              u16* __restrict__ h) {
    int bid = blockIdx.x;
    int tid = threadIdx.x;
    if (bid < 1280) {
        __shared__ float tl[32][65];
        const float* src; u16* dst; int K, C, rel;
        if (bid < 256)      { src = Wg; dst = wgP; K = 256;  C = 512;  rel = bid; }
        else if (bid < 512) { src = Wu; dst = wuP; K = 256;  C = 512;  rel = bid - 256; }
        else if (bid < 768) { src = Wd; dst = wdP; K = 512;  C = 256;  rel = bid - 512; }
        else                { src = Wo; dst = woP; K = 1024; C = 1024; rel = bid - 768; }
        int ncb = C >> 6, nkt = K >> 5;
        int cb = rel % ncb; int r2 = rel / ncb;
        int kt = r2 % nkt;  int b  = r2 / nkt;
        {
            int r = tid >> 3, c0 = (tid & 7) * 8;
            const float* s = src + ((size_t)(b * K + kt * 32 + r)) * C + cb * 64 + c0;
            float4 v0 = *(const float4*)(s);
            float4 v1 = *(const float4*)(s + 4);
            tl[r][c0 + 0] = v0.x; tl[r][c0 + 1] = v0.y; tl[r][c0 + 2] = v0.z; tl[r][c0 + 3] = v0.w;
            tl[r][c0 + 4] = v1.x; tl[r][c0 + 5] = v1.y; tl[r][c0 + 6] = v1.z; tl[r][c0 + 7] = v1.w;
        }
        __syncthreads();
        {
            int f = tid >> 6, l = tid & 63;
            union { u16 v[8]; uint4 q; } u;
#pragma unroll
            for (int j = 0; j < 8; ++j)
                u.v[j] = f2bf(tl[(l >> 4) * 8 + j][f * 16 + (l & 15)]);
            size_t ctile = (size_t)(b * (C >> 4) + cb * 4 + f);
            *(uint4*)(dst + (ctile * nkt + kt) * 512 + l * 8) = u.q;
        }
        return;
    }
    // ---- norm + rope
    int tok = bid - 1280;
    int s = tok & (S_LEN - 1);
    int t = tid;
    const float* xr = x + (size_t)tok * DMODEL;
    float x0 = xr[t], x1 = xr[t + 256], x2 = xr[t + 512], x3 = xr[t + 768];
    float ss = x0 * x0 + x1 * x1 + x2 * x2 + x3 * x3;
#pragma unroll
    for (int o = 32; o > 0; o >>= 1) ss += __shfl_down(ss, o, 64);
    __shared__ float red[4];
    if ((t & 63) == 0) red[t >> 6] = ss;
    __syncthreads();
    float tot = red[0] + red[1] + red[2] + red[3];
    float sc = rsqrtf(tot * (1.0f / DMODEL) + 1e-6f);
    float n0 = x0 * sc * nw[t];
    float n1 = x1 * sc * nw[t + 256];
    float n2 = x2 * sc * nw[t + 512];
    float n3 = x3 * sc * nw[t + 768];
    const float C = -0.017988946039015984f;   // -ln(10000)/512
    float sf = (float)s;
    float ang0 = sf * expf(C * (float)t);
    float ang1 = sf * expf(C * (float)(t + 256));
    float sn0, cs0, sn1, cs1;
    sincosf(ang0, &sn0, &cs0);
    sincosf(ang1, &sn1, &cs1);
    u16* hr = h + (size_t)tok * DMODEL;
    hr[t]       = f2bf(n0 * cs0 - n2 * sn0);
    hr[t + 256] = f2bf(n1 * cs1 - n3 * sn1);
    hr[t + 512] = f2bf(n2 * cs0 + n0 * sn0);
    hr[t + 768] = f2bf(n3 * cs1 + n1 * sn1);
}

// ---------------------------------------------------------- grouped SwiGLU
// R25 EXACT (best measured: 76.6us swiglu, 152.6us total). K-widened
// depth-3 ring (24 stages x 4KB, 2 K-steps each), steady vmcnt(8), hard
// LGKM0 before ISSUE(t+3) (slot collision), setprio MFMA clusters, rcp
// silu, sT double-buffered (4 barriers). LDS 160KB. R26's issue-dist-2
// variant regressed (cover dropped below L2 latency).
__global__ __launch_bounds__(512, 1)
void k_swiglu(const u16* __restrict__ h,
              const u16* __restrict__ wgP,   // [4][32][8][64][8]
              const u16* __restrict__ wuP,   // [4][32][8][64][8]
              const u16* __restrict__ wdP,   // [4][16][16][64][8]
              u16* __restrict__ dmid) {
    int bid = blockIdx.x;
    int mb = bid & 255, n = bid >> 8;
    int m0 = mb * 64;
    int tid = threadIdx.x;
    int lane = tid & 63, wid = tid >> 6;

    __shared__ u16 hA[64 * 256];          // 32KB, swizzled
    __shared__ u16 sT[2][64 * 128];       // 2 x 16KB, swizzled
    __shared__ u16 sW[8 * 3 * 2048];      // 96KB [wave][ring3][4 slots x 512]

    const u16* wg = wgP + (size_t)n * (32 * 8 * 512);
    const u16* wu = wuP + (size_t)n * (32 * 8 * 512);
    const u16* wd = wdP + (size_t)n * (16 * 16 * 512);
    u16* myW = sW + wid * 6144;

    // stage t (0..23): hc=t/6, r=t%6; r<4 -> gu ks={2r,2r+1};
    // r in {4,5} -> down k2={2(r-4), 2(r-4)+1}
#define ISSUE(t)                                                               \
    do {                                                                       \
        if ((t) < 24) {                                                        \
            const int hcs = (t) / 6, rs = (t) % 6;                             \
            u16* db = myW + ((t) % 3) * 2048;                                  \
            if (rs < 4) {                                                      \
                size_t ct0 = (size_t)(hcs * 8 + wid);                          \
                const int ks0 = rs * 2;                                        \
                gl_lds16(wg + (ct0 * 8 + ks0) * 512 + lane * 8, db);           \
                gl_lds16(wu + (ct0 * 8 + ks0) * 512 + lane * 8, db + 512);     \
                gl_lds16(wg + (ct0 * 8 + ks0 + 1) * 512 + lane * 8, db + 1024);\
                gl_lds16(wu + (ct0 * 8 + ks0 + 1) * 512 + lane * 8, db + 1536);\
            } else {                                                           \
                const int k20 = (rs - 4) * 2;                                  \
                gl_lds16(wd + ((size_t)(wid * 2 + 0) * 16 + hcs * 4 + k20) * 512 + lane * 8, db);            \
                gl_lds16(wd + ((size_t)(wid * 2 + 1) * 16 + hcs * 4 + k20) * 512 + lane * 8, db + 512);      \
                gl_lds16(wd + ((size_t)(wid * 2 + 0) * 16 + hcs * 4 + k20 + 1) * 512 + lane * 8, db + 1024); \
                gl_lds16(wd + ((size_t)(wid * 2 + 1) * 16 + hcs * 4 + k20 + 1) * 512 + lane * 8, db + 1536); \
            }                                                                  \
        }                                                                      \
    } while (0)
    // wait until stage t's 4 loads landed (stages t+1,t+2 may be in flight)
#define VMW(t)                                                                 \
    do {                                                                       \
        if ((t) <= 21)      asm volatile("s_waitcnt vmcnt(8)" ::: "memory");   \
        else if ((t) == 22) asm volatile("s_waitcnt vmcnt(4)" ::: "memory");   \
        else                asm volatile("s_waitcnt vmcnt(0)" ::: "memory");   \
    } while (0)

    // ---- prologue: h tile -> regs (oldest vmem), ring 0..2, then hA
    const u16* hbase = h + (size_t)m0 * DMODEL + n * DSUB;
    uint4 hv[4];
#pragma unroll
    for (int it = 0; it < 4; ++it) {
        int e = (tid + it * 512) * 8;
        int r = e >> 8, c = e & 255;
        hv[it] = *(const uint4*)(hbase + (size_t)r * DMODEL + c);
    }
    ISSUE(0); ISSUE(1); ISSUE(2);
#pragma unroll
    for (int it = 0; it < 4; ++it) {
        int e = (tid + it * 512) * 8;
        int r = e >> 8, c = e & 255;
        u32 off = ((u32)(r * 512 + c * 2)) ^ ((u32)(r & 7) << 4);
        *(uint4*)((char*)hA + off) = hv[it];
    }
    LGKM0; SBAR;

    const f32x4 zero = {0.f, 0.f, 0.f, 0.f};
    f32x4 accd[4][2];
#pragma unroll
    for (int a = 0; a < 4; ++a) { accd[a][0] = zero; accd[a][1] = zero; }

#pragma unroll
    for (int hc = 0; hc < 4; ++hc) {
        // ======== gate/up: 4 wide stages (2 K-steps each)
        f32x4 accg[4], accu[4];
#pragma unroll
        for (int a = 0; a < 4; ++a) { accg[a] = zero; accu[a] = zero; }

#pragma unroll
        for (int ks2 = 0; ks2 < 4; ++ks2) {
            const int t = hc * 6 + ks2;
            VMW(t); SCHED0;
            const u16* rb = myW + (t % 3) * 2048;
            bf16x8 bg0 = *(const bf16x8*)(rb + lane * 8);
            bf16x8 bu0 = *(const bf16x8*)(rb + 512 + lane * 8);
            bf16x8 bg1 = *(const bf16x8*)(rb + 1024 + lane * 8);
            bf16x8 bu1 = *(const bf16x8*)(rb + 1536 + lane * 8);
            LGKM0; SCHED0;            // weights in regs before slot reuse
            ISSUE(t + 3);
            __builtin_amdgcn_s_setprio(1);
#pragma unroll
            for (int half = 0; half < 2; ++half) {
                const int ks = ks2 * 2 + half;
#pragma unroll
                for (int rt = 0; rt < 4; ++rt) {
                    int arow = rt * 16 + (lane & 15);
                    int k0 = ks * 32 + (lane >> 4) * 8;
                    u32 off = ((u32)(arow * 512 + k0 * 2)) ^ ((u32)(arow & 7) << 4);
                    bf16x8 afr = *(const bf16x8*)((const char*)hA + off);
                    accg[rt] = MFMA16(afr, half ? bg1 : bg0, accg[rt]);
                    accu[rt] = MFMA16(afr, half ? bu1 : bu0, accu[rt]);
                }
            }
            __builtin_amdgcn_s_setprio(0);
        }

        // ======== t = silu(g)*u -> sT[hc&1] (swizzled scatter); rcp silu
        u16* sTc = (u16*)sT[hc & 1];
#pragma unroll
        for (int rt = 0; rt < 4; ++rt) {
            int rbase = rt * 16 + (lane >> 4) * 4;
            int col = wid * 16 + (lane & 15);
#pragma unroll
            for (int q = 0; q < 4; ++q) {
                float g = accg[rt][q], u = accu[rt][q];
                float tv = g * u * __builtin_amdgcn_rcpf(1.0f + __expf(-g));
                int row = rbase + q;
                u32 off = ((u32)(row * 256 + col * 2)) ^ ((u32)(row & 7) << 4);
                *(u16*)((char*)sTc + off) = f2bf(tv);
            }
        }
        LGKM0; SBAR;                  // publish sT[hc&1]; ring stays in flight

        // ======== down: 2 wide stages (2 K-steps each)
#pragma unroll
        for (int k22 = 0; k22 < 2; ++k22) {
            const int t = hc * 6 + 4 + k22;
            VMW(t); SCHED0;
            const u16* rb = myW + (t % 3) * 2048;
            bf16x8 bdA0 = *(const bf16x8*)(rb + lane * 8);
            bf16x8 bdB0 = *(const bf16x8*)(rb + 512 + lane * 8);
            bf16x8 bdA1 = *(const bf16x8*)(rb + 1024 + lane * 8);
            bf16x8 bdB1 = *(const bf16x8*)(rb + 1536 + lane * 8);
            LGKM0; SCHED0;
            ISSUE(t + 3);
            __builtin_amdgcn_s_setprio(1);
#pragma unroll
            for (int half = 0; half < 2; ++half) {
                const int k2 = k22 * 2 + half;
#pragma unroll
                for (int rt = 0; rt < 4; ++rt) {
                    int arow = rt * 16 + (lane & 15);
                    int k0 = k2 * 32 + (lane >> 4) * 8;
                    u32 off = ((u32)(arow * 256 + k0 * 2)) ^ ((u32)(arow & 7) << 4);
                    bf16x8 afr = *(const bf16x8*)((const char*)sTc + off);
                    accd[rt][0] = MFMA16(afr, half ? bdA1 : bdA0, accd[rt][0]);
                    accd[rt][1] = MFMA16(afr, half ? bdB1 : bdB0, accd[rt][1]);
                }
            }
            __builtin_amdgcn_s_setprio(0);
        }
        // no barrier: next silu writes sT[(hc+1)&1]; all readers of that
        // buffer (down(hc-1)) completed before the silu(hc) barrier above
    }
#undef ISSUE
#undef VMW

    // ---- write dmid [64][256] n-slice as bf16
#pragma unroll
    for (int rt = 0; rt < 4; ++rt)
#pragma unroll
        for (int ct = 0; ct < 2; ++ct) {
            int rbase = m0 + rt * 16 + (lane >> 4) * 4;
            int col = n * DSUB + wid * 32 + ct * 16 + (lane & 15);
#pragma unroll
            for (int q = 0; q < 4; ++q)
                dmid[(size_t)(rbase + q) * DMODEL + col] = f2bf(accd[rt][ct][q]);
        }
}

// -------------------------------------------------- final GEMM + residual
// R8 loop structure + residual-init (best measured ~27-34us): acc loaded
// from x in the PROLOGUE (overlaps chunk-0 staging), store-only epilogue.
__global__ __launch_bounds__(512, 2) void k_final(const u16* __restrict__ dmid,
                                                  const u16* __restrict__ woP,   // [64][32][64][8]
                                                  const float* __restrict__ x,
                                                  float* __restrict__ out) {
    int bid = blockIdx.x;
    int mb = bid & 127, nb = bid >> 7;
    int m0 = mb * 128, n0 = nb * 256;
    int tid = threadIdx.x;
    int lane = tid & 63, wid = tid >> 6;
    int wr = wid >> 2, wc = wid & 3;

    __shared__ u16 sA[2][128 * 256];     // 2 x 64KB, swizzled

    f32x4 acc[4][4];
    const u16* dbase = dmid + (size_t)m0 * DMODEL;

    uint4 stA[8], stB[8];
    // chunk 0 -> stA, write sA[0]
#pragma unroll
    for (int it = 0; it < 8; ++it) {
        int e = (tid + it * 512) * 8;
        int r = e >> 8, c = e & 255;
        stA[it] = *(const uint4*)(dbase + (size_t)r * DMODEL + c);
    }
    // init acc from residual x (read overlaps staging; epilogue = store only)
#pragma unroll
    for (int rt = 0; rt < 4; ++rt)
#pragma unroll
        for (int ct = 0; ct < 4; ++ct) {
            int rbase = m0 + wr * 64 + rt * 16 + (lane >> 4) * 4;
            int col = n0 + wc * 64 + ct * 16 + (lane & 15);
#pragma unroll
            for (int q = 0; q < 4; ++q)
                acc[rt][ct][q] = x[(size_t)(rbase + q) * DMODEL + col];
        }
#pragma unroll
    for (int it = 0; it < 8; ++it) {
        int e = (tid + it * 512) * 8;
        int r = e >> 8, c = e & 255;
        u32 off = ((u32)(r * 512 + c * 2)) ^ ((u32)(r & 7) << 4);
        *(uint4*)((char*)sA[0] + off) = stA[it];
    }
    // issue chunk 1 -> stB
#pragma unroll
    for (int it = 0; it < 8; ++it) {
        int e = (tid + it * 512) * 8;
        int r = e >> 8, c = e & 255;
        stB[it] = *(const uint4*)(dbase + (size_t)r * DMODEL + 256 + c);
    }

#pragma unroll
    for (int kc = 0; kc < 4; ++kc) {
        __syncthreads();                       // sA[kc&1] ready
        if (kc < 3) {                          // write chunk kc+1 into sA[(kc+1)&1]
#pragma unroll
            for (int it = 0; it < 8; ++it) {
                int e = (tid + it * 512) * 8;
                int r = e >> 8, c = e & 255;
                u32 off = ((u32)(r * 512 + c * 2)) ^ ((u32)(r & 7) << 4);
                uint4 v = (kc & 1) ? stA[it] : stB[it];
                *(uint4*)((char*)sA[(kc + 1) & 1] + off) = v;
            }
        }
        if (kc < 2) {                          // issue chunk kc+2
#pragma unroll
            for (int it = 0; it < 8; ++it) {
                int e = (tid + it * 512) * 8;
                int r = e >> 8, c = e & 255;
                uint4 v = *(const uint4*)(dbase + (size_t)r * DMODEL + (kc + 2) * 256 + c);
                if ((kc & 1) == 0) stA[it] = v; else stB[it] = v;
            }
        }

        const u16* sAc = (const u16*)sA[kc & 1];
        bf16x8 wf[2][4];
#pragma unroll
        for (int ct = 0; ct < 4; ++ct) {
            size_t ctile = (size_t)(nb * 16 + wc * 4 + ct);
            size_t ktile = (size_t)(kc * 8 + 0);
            wf[0][ct] = *(const bf16x8*)(woP + (ctile * 32 + ktile) * 512 + lane * 8);
        }
#pragma unroll
        for (int ks = 0; ks < 8; ++ks) {
            if (ks < 7) {
#pragma unroll
                for (int ct = 0; ct < 4; ++ct) {
                    size_t ctile = (size_t)(nb * 16 + wc * 4 + ct);
                    size_t ktile = (size_t)(kc * 8 + ks + 1);
                    wf[(ks + 1) & 1][ct] = *(const bf16x8*)(woP + (ctile * 32 + ktile) * 512 + lane * 8);
                }
            }
            bf16x8 afr[4];
#pragma unroll
            for (int rt = 0; rt < 4; ++rt) {
                int arow = wr * 64 + rt * 16 + (lane & 15);
                int k0 = ks * 32 + (lane >> 4) * 8;
                u32 off = ((u32)(arow * 512 + k0 * 2)) ^ ((u32)(arow & 7) << 4);
                afr[rt] = *(const bf16x8*)((const char*)sAc + off);
            }
#pragma unroll
            for (int ct = 0; ct < 4; ++ct)
#pragma unroll
                for (int rt = 0; rt < 4; ++rt)
                    acc[rt][ct] = MFMA16(afr[rt], wf[ks & 1][ct], acc[rt][ct]);
        }
    }

    // epilogue: store only (residual already folded into acc init)
#pragma unroll
    for (int rt = 0; rt < 4; ++rt)
#pragma unroll
        for (int ct = 0; ct < 4; ++ct) {
            int rbase = m0 + wr * 64 + rt * 16 + (lane >> 4) * 4;
            int col = n0 + wc * 64 + ct * 16 + (lane & 15);
#pragma unroll
            for (int q = 0; q < 4; ++q) {
                size_t o = (size_t)(rbase + q) * DMODEL + col;
                out[o] = acc[rt][ct][q];
            }
        }
}

// ---------------------------------------------------------------- launcher
extern "C" void kernel_launch(void* const* d_in, const int* in_sizes, int n_in,
                              void* d_out, int out_size, void* d_ws, size_t ws_size,
                              hipStream_t stream) {
    const float* x  = (const float*)d_in[0];
    const float* nw = (const float*)d_in[1];
    const float* Wg = (const float*)d_in[2];
    const float* Wu = (const float*)d_in[3];
    const float* Wd = (const float*)d_in[4];
    const float* Wo = (const float*)d_in[5];
    float* out = (float*)d_out;

    char* ws = (char*)d_ws;
    const size_t MB = 1u << 20;
    u16* h    = (u16*)(ws);             // 32 MB
    u16* wgP  = (u16*)(ws + 32 * MB);   //  1 MB
    u16* wuP  = (u16*)(ws + 33 * MB);   //  1 MB
    u16* wdP  = (u16*)(ws + 34 * MB);   //  1 MB
    u16* woP  = (u16*)(ws + 35 * MB);   //  2 MB
    u16* dmid = (u16*)(ws + 37 * MB);   // 32 MB  (end: 69 MB)

    k_prep<<<1280 + NTOK, 256, 0, stream>>>(Wg, Wu, Wd, Wo, x, nw,
                                            wgP, wuP, wdP, woP, h);
    k_swiglu<<<256 * NSUB, 512, 0, stream>>>(h, wgP, wuP, wdP, dmid);
    k_final<<<128 * 4, 512, 0, stream>>>(dmid, woP, x, out);
}

// Round 28
// 151.275 us; speedup vs baseline: 1.0218x; 1.0102x over previous
//
#include <hip/hip_runtime.h>

typedef unsigned short u16;
typedef unsigned int   u32;

typedef float  f32x4  __attribute__((ext_vector_type(4)));
typedef __bf16 bf16x8 __attribute__((ext_vector_type(8)));

#define S_LEN  4096
#define DMODEL 1024
#define NSUB   4
#define DSUB   256
#define HFF    512
#define NTOK   16384   // B*S = 4*4096

static_assert(sizeof(bf16x8) == 16, "frag size");

__device__ __forceinline__ u16 f2bf(float f) {
    union { float f; u32 u; } v; v.f = f;
    u32 r = (v.u + 0x7fffu + ((v.u >> 16) & 1u)) >> 16;   // RNE
    return (u16)r;
}

#define MFMA16(a, b, c) __builtin_amdgcn_mfma_f32_16x16x32_bf16((a), (b), (c), 0, 0, 0)

// async global->LDS, 16B per lane: per-lane global src, wave-uniform LDS base
__device__ __forceinline__ void gl_lds16(const void* g, void* l) {
    __builtin_amdgcn_global_load_lds(
        (const __attribute__((address_space(1))) void*)g,
        (__attribute__((address_space(3))) void*)l,
        16, 0, 0);
}
#define LGKM0 asm volatile("s_waitcnt lgkmcnt(0)" ::: "memory")
#define SCHED0 __builtin_amdgcn_sched_barrier(0)
#define SBAR __builtin_amdgcn_s_barrier()

// ---------------------- merged prep: weight repack + RMSNorm/RoPE
// blocks [0,1280): fragment-packed repack
//   dst[b][C/16][K/32][lane 64][8] = bf16(src[b][k][c]),
//   k = kt*32 + (lane>>4)*8 + j, c = ct*16 + (lane&15)
// blocks [1280, 1280+16384): norm+rope for token (bid-1280)
__global__ __launch_bounds__(256) void k_prep(const float* __restrict__ Wg,
                                              const float* __restrict__ Wu,
                                              const float* __restrict__ Wd,
                                              const float* __restrict__ Wo,
                                              const float* __restrict__ x,
                                              const float* __restrict__ nw,
                                              u16* __restrict__ wgP,
                                              u16* __restrict__ wuP,
                                              u16* __restrict__ wdP,
                                              u16* __restrict__ woP,
                                              u16* __restrict__ h) {
    int bid = blockIdx.x;
    int tid = threadIdx.x;
    if (bid < 1280) {
        __shared__ float tl[32][65];
        const float* src; u16* dst; int K, C, rel;
        if (bid < 256)      { src = Wg; dst = wgP; K = 256;  C = 512;  rel = bid; }
        else if (bid < 512) { src = Wu; dst = wuP; K = 256;  C = 512;  rel = bid - 256; }
        else if (bid < 768) { src = Wd; dst = wdP; K = 512;  C = 256;  rel = bid - 512; }
        else                { src = Wo; dst = woP; K = 1024; C = 1024; rel = bid - 768; }
        int ncb = C >> 6, nkt = K >> 5;
        int cb = rel % ncb; int r2 = rel / ncb;
        int kt = r2 % nkt;  int b  = r2 / nkt;
        {
            int r = tid >> 3, c0 = (tid & 7) * 8;
            const float* s = src + ((size_t)(b * K + kt * 32 + r)) * C + cb * 64 + c0;
            float4 v0 = *(const float4*)(s);
            float4 v1 = *(const float4*)(s + 4);
            tl[r][c0 + 0] = v0.x; tl[r][c0 + 1] = v0.y; tl[r][c0 + 2] = v0.z; tl[r][c0 + 3] = v0.w;
            tl[r][c0 + 4] = v1.x; tl[r][c0 + 5] = v1.y; tl[r][c0 + 6] = v1.z; tl[r][c0 + 7] = v1.w;
        }
        __syncthreads();
        {
            int f = tid >> 6, l = tid & 63;
            union { u16 v[8]; uint4 q; } u;
#pragma unroll
            for (int j = 0; j < 8; ++j)
                u.v[j] = f2bf(tl[(l >> 4) * 8 + j][f * 16 + (l & 15)]);
            size_t ctile = (size_t)(b * (C >> 4) + cb * 4 + f);
            *(uint4*)(dst + (ctile * nkt + kt) * 512 + l * 8) = u.q;
        }
        return;
    }
    // ---- norm + rope
    int tok = bid - 1280;
    int s = tok & (S_LEN - 1);
    int t = tid;
    const float* xr = x + (size_t)tok * DMODEL;
    float x0 = xr[t], x1 = xr[t + 256], x2 = xr[t + 512], x3 = xr[t + 768];
    float ss = x0 * x0 + x1 * x1 + x2 * x2 + x3 * x3;
#pragma unroll
    for (int o = 32; o > 0; o >>= 1) ss += __shfl_down(ss, o, 64);
    __shared__ float red[4];
    if ((t & 63) == 0) red[t >> 6] = ss;
    __syncthreads();
    float tot = red[0] + red[1] + red[2] + red[3];
    float sc = rsqrtf(tot * (1.0f / DMODEL) + 1e-6f);
    float n0 = x0 * sc * nw[t];
    float n1 = x1 * sc * nw[t + 256];
    float n2 = x2 * sc * nw[t + 512];
    float n3 = x3 * sc * nw[t + 768];
    const float C = -0.017988946039015984f;   // -ln(10000)/512
    float sf = (float)s;
    float ang0 = sf * expf(C * (float)t);
    float ang1 = sf * expf(C * (float)(t + 256));
    float sn0, cs0, sn1, cs1;
    sincosf(ang0, &sn0, &cs0);
    sincosf(ang1, &sn1, &cs1);
    u16* hr = h + (size_t)tok * DMODEL;
    hr[t]       = f2bf(n0 * cs0 - n2 * sn0);
    hr[t + 256] = f2bf(n1 * cs1 - n3 * sn1);
    hr[t + 512] = f2bf(n2 * cs0 + n0 * sn0);
    hr[t + 768] = f2bf(n3 * cs1 + n1 * sn1);
}

// ---------------------------------------------------------- grouped SwiGLU
// FINAL (best measured: 76.6us swiglu, 152.6-152.8us total, verified twice).
// K-widened depth-3 ring (24 stages x 4KB, 2 K-steps each), steady vmcnt(8),
// hard LGKM0 before ISSUE(t+3) (slot collision), setprio MFMA clusters, rcp
// silu, sT double-buffered (4 barriers). LDS 160KB, VGPR 108, no spill.
__global__ __launch_bounds__(512, 1)
void k_swiglu(const u16* __restrict__ h,
              const u16* __restrict__ wgP,   // [4][32][8][64][8]
              const u16* __restrict__ wuP,   // [4][32][8][64][8]
              const u16* __restrict__ wdP,   // [4][16][16][64][8]
              u16* __restrict__ dmid) {
    int bid = blockIdx.x;
    int mb = bid & 255, n = bid >> 8;
    int m0 = mb * 64;
    int tid = threadIdx.x;
    int lane = tid & 63, wid = tid >> 6;

    __shared__ u16 hA[64 * 256];          // 32KB, swizzled
    __shared__ u16 sT[2][64 * 128];       // 2 x 16KB, swizzled
    __shared__ u16 sW[8 * 3 * 2048];      // 96KB [wave][ring3][4 slots x 512]

    const u16* wg = wgP + (size_t)n * (32 * 8 * 512);
    const u16* wu = wuP + (size_t)n * (32 * 8 * 512);
    const u16* wd = wdP + (size_t)n * (16 * 16 * 512);
    u16* myW = sW + wid * 6144;

    // stage t (0..23): hc=t/6, r=t%6; r<4 -> gu ks={2r,2r+1};
    // r in {4,5} -> down k2={2(r-4), 2(r-4)+1}
#define ISSUE(t)                                                               \
    do {                                                                       \
        if ((t) < 24) {                                                        \
            const int hcs = (t) / 6, rs = (t) % 6;                             \
            u16* db = myW + ((t) % 3) * 2048;                                  \
            if (rs < 4) {                                                      \
                size_t ct0 = (size_t)(hcs * 8 + wid);                          \
                const int ks0 = rs * 2;                                        \
                gl_lds16(wg + (ct0 * 8 + ks0) * 512 + lane * 8, db);           \
                gl_lds16(wu + (ct0 * 8 + ks0) * 512 + lane * 8, db + 512);     \
                gl_lds16(wg + (ct0 * 8 + ks0 + 1) * 512 + lane * 8, db + 1024);\
                gl_lds16(wu + (ct0 * 8 + ks0 + 1) * 512 + lane * 8, db + 1536);\
            } else {                                                           \
                const int k20 = (rs - 4) * 2;                                  \
                gl_lds16(wd + ((size_t)(wid * 2 + 0) * 16 + hcs * 4 + k20) * 512 + lane * 8, db);            \
                gl_lds16(wd + ((size_t)(wid * 2 + 1) * 16 + hcs * 4 + k20) * 512 + lane * 8, db + 512);      \
                gl_lds16(wd + ((size_t)(wid * 2 + 0) * 16 + hcs * 4 + k20 + 1) * 512 + lane * 8, db + 1024); \
                gl_lds16(wd + ((size_t)(wid * 2 + 1) * 16 + hcs * 4 + k20 + 1) * 512 + lane * 8, db + 1536); \
            }                                                                  \
        }                                                                      \
    } while (0)
    // wait until stage t's 4 loads landed (stages t+1,t+2 may be in flight)
#define VMW(t)                                                                 \
    do {                                                                       \
        if ((t) <= 21)      asm volatile("s_waitcnt vmcnt(8)" ::: "memory");   \
        else if ((t) == 22) asm volatile("s_waitcnt vmcnt(4)" ::: "memory");   \
        else                asm volatile("s_waitcnt vmcnt(0)" ::: "memory");   \
    } while (0)

    // ---- prologue: h tile -> regs (oldest vmem), ring 0..2, then hA
    const u16* hbase = h + (size_t)m0 * DMODEL + n * DSUB;
    uint4 hv[4];
#pragma unroll
    for (int it = 0; it < 4; ++it) {
        int e = (tid + it * 512) * 8;
        int r = e >> 8, c = e & 255;
        hv[it] = *(const uint4*)(hbase + (size_t)r * DMODEL + c);
    }
    ISSUE(0); ISSUE(1); ISSUE(2);
#pragma unroll
    for (int it = 0; it < 4; ++it) {
        int e = (tid + it * 512) * 8;
        int r = e >> 8, c = e & 255;
        u32 off = ((u32)(r * 512 + c * 2)) ^ ((u32)(r & 7) << 4);
        *(uint4*)((char*)hA + off) = hv[it];
    }
    LGKM0; SBAR;

    const f32x4 zero = {0.f, 0.f, 0.f, 0.f};
    f32x4 accd[4][2];
#pragma unroll
    for (int a = 0; a < 4; ++a) { accd[a][0] = zero; accd[a][1] = zero; }

#pragma unroll
    for (int hc = 0; hc < 4; ++hc) {
        // ======== gate/up: 4 wide stages (2 K-steps each)
        f32x4 accg[4], accu[4];
#pragma unroll
        for (int a = 0; a < 4; ++a) { accg[a] = zero; accu[a] = zero; }

#pragma unroll
        for (int ks2 = 0; ks2 < 4; ++ks2) {
            const int t = hc * 6 + ks2;
            VMW(t); SCHED0;
            const u16* rb = myW + (t % 3) * 2048;
            bf16x8 bg0 = *(const bf16x8*)(rb + lane * 8);
            bf16x8 bu0 = *(const bf16x8*)(rb + 512 + lane * 8);
            bf16x8 bg1 = *(const bf16x8*)(rb + 1024 + lane * 8);
            bf16x8 bu1 = *(const bf16x8*)(rb + 1536 + lane * 8);
            LGKM0; SCHED0;            // weights in regs before slot reuse
            ISSUE(t + 3);
            __builtin_amdgcn_s_setprio(1);
#pragma unroll
            for (int half = 0; half < 2; ++half) {
                const int ks = ks2 * 2 + half;
#pragma unroll
                for (int rt = 0; rt < 4; ++rt) {
                    int arow = rt * 16 + (lane & 15);
                    int k0 = ks * 32 + (lane >> 4) * 8;
                    u32 off = ((u32)(arow * 512 + k0 * 2)) ^ ((u32)(arow & 7) << 4);
                    bf16x8 afr = *(const bf16x8*)((const char*)hA + off);
                    accg[rt] = MFMA16(afr, half ? bg1 : bg0, accg[rt]);
                    accu[rt] = MFMA16(afr, half ? bu1 : bu0, accu[rt]);
                }
            }
            __builtin_amdgcn_s_setprio(0);
        }

        // ======== t = silu(g)*u -> sT[hc&1] (swizzled scatter); rcp silu
        u16* sTc = (u16*)sT[hc & 1];
#pragma unroll
        for (int rt = 0; rt < 4; ++rt) {
            int rbase = rt * 16 + (lane >> 4) * 4;
            int col = wid * 16 + (lane & 15);
#pragma unroll
            for (int q = 0; q < 4; ++q) {
                float g = accg[rt][q], u = accu[rt][q];
                float tv = g * u * __builtin_amdgcn_rcpf(1.0f + __expf(-g));
                int row = rbase + q;
                u32 off = ((u32)(row * 256 + col * 2)) ^ ((u32)(row & 7) << 4);
                *(u16*)((char*)sTc + off) = f2bf(tv);
            }
        }
        LGKM0; SBAR;                  // publish sT[hc&1]; ring stays in flight

        // ======== down: 2 wide stages (2 K-steps each)
#pragma unroll
        for (int k22 = 0; k22 < 2; ++k22) {
            const int t = hc * 6 + 4 + k22;
            VMW(t); SCHED0;
            const u16* rb = myW + (t % 3) * 2048;
            bf16x8 bdA0 = *(const bf16x8*)(rb + lane * 8);
            bf16x8 bdB0 = *(const bf16x8*)(rb + 512 + lane * 8);
            bf16x8 bdA1 = *(const bf16x8*)(rb + 1024 + lane * 8);
            bf16x8 bdB1 = *(const bf16x8*)(rb + 1536 + lane * 8);
            LGKM0; SCHED0;
            ISSUE(t + 3);
            __builtin_amdgcn_s_setprio(1);
#pragma unroll
            for (int half = 0; half < 2; ++half) {
                const int k2 = k22 * 2 + half;
#pragma unroll
                for (int rt = 0; rt < 4; ++rt) {
                    int arow = rt * 16 + (lane & 15);
                    int k0 = k2 * 32 + (lane >> 4) * 8;
                    u32 off = ((u32)(arow * 256 + k0 * 2)) ^ ((u32)(arow & 7) << 4);
                    bf16x8 afr = *(const bf16x8*)((const char*)sTc + off);
                    accd[rt][0] = MFMA16(afr, half ? bdA1 : bdA0, accd[rt][0]);
                    accd[rt][1] = MFMA16(afr, half ? bdB1 : bdB0, accd[rt][1]);
                }
            }
            __builtin_amdgcn_s_setprio(0);
        }
        // no barrier: next silu writes sT[(hc+1)&1]; all readers of that
        // buffer (down(hc-1)) completed before the silu(hc) barrier above
    }
#undef ISSUE
#undef VMW

    // ---- write dmid [64][256] n-slice as bf16
#pragma unroll
    for (int rt = 0; rt < 4; ++rt)
#pragma unroll
        for (int ct = 0; ct < 2; ++ct) {
            int rbase = m0 + rt * 16 + (lane >> 4) * 4;
            int col = n * DSUB + wid * 32 + ct * 16 + (lane & 15);
#pragma unroll
            for (int q = 0; q < 4; ++q)
                dmid[(size_t)(rbase + q) * DMODEL + col] = f2bf(accd[rt][ct][q]);
        }
}

// -------------------------------------------------- final GEMM + residual
// R8 loop structure + residual-init: acc loaded from x in the PROLOGUE
// (overlaps chunk-0 staging), store-only epilogue. ~28us (HBM floor ~25).
__global__ __launch_bounds__(512, 2) void k_final(const u16* __restrict__ dmid,
                                                  const u16* __restrict__ woP,   // [64][32][64][8]
                                                  const float* __restrict__ x,
                                                  float* __restrict__ out) {
    int bid = blockIdx.x;
    int mb = bid & 127, nb = bid >> 7;
    int m0 = mb * 128, n0 = nb * 256;
    int tid = threadIdx.x;
    int lane = tid & 63, wid = tid >> 6;
    int wr = wid >> 2, wc = wid & 3;

    __shared__ u16 sA[2][128 * 256];     // 2 x 64KB, swizzled

    f32x4 acc[4][4];
    const u16* dbase = dmid + (size_t)m0 * DMODEL;

    uint4 stA[8], stB[8];
    // chunk 0 -> stA, write sA[0]
#pragma unroll
    for (int it = 0; it < 8; ++it) {
        int e = (tid + it * 512) * 8;
        int r = e >> 8, c = e & 255;
        stA[it] = *(const uint4*)(dbase + (size_t)r * DMODEL + c);
    }
    // init acc from residual x (read overlaps staging; epilogue = store only)
#pragma unroll
    for (int rt = 0; rt < 4; ++rt)
#pragma unroll
        for (int ct = 0; ct < 4; ++ct) {
            int rbase = m0 + wr * 64 + rt * 16 + (lane >> 4) * 4;
            int col = n0 + wc * 64 + ct * 16 + (lane & 15);
#pragma unroll
            for (int q = 0; q < 4; ++q)
                acc[rt][ct][q] = x[(size_t)(rbase + q) * DMODEL + col];
        }
#pragma unroll
    for (int it = 0; it < 8; ++it) {
        int e = (tid + it * 512) * 8;
        int r = e >> 8, c = e & 255;
        u32 off = ((u32)(r * 512 + c * 2)) ^ ((u32)(r & 7) << 4);
        *(uint4*)((char*)sA[0] + off) = stA[it];
    }
    // issue chunk 1 -> stB
#pragma unroll
    for (int it = 0; it < 8; ++it) {
        int e = (tid + it * 512) * 8;
        int r = e >> 8, c = e & 255;
        stB[it] = *(const uint4*)(dbase + (size_t)r * DMODEL + 256 + c);
    }

#pragma unroll
    for (int kc = 0; kc < 4; ++kc) {
        __syncthreads();                       // sA[kc&1] ready
        if (kc < 3) {                          // write chunk kc+1 into sA[(kc+1)&1]
#pragma unroll
            for (int it = 0; it < 8; ++it) {
                int e = (tid + it * 512) * 8;
                int r = e >> 8, c = e & 255;
                u32 off = ((u32)(r * 512 + c * 2)) ^ ((u32)(r & 7) << 4);
                uint4 v = (kc & 1) ? stA[it] : stB[it];
                *(uint4*)((char*)sA[(kc + 1) & 1] + off) = v;
            }
        }
        if (kc < 2) {                          // issue chunk kc+2
#pragma unroll
            for (int it = 0; it < 8; ++it) {
                int e = (tid + it * 512) * 8;
                int r = e >> 8, c = e & 255;
                uint4 v = *(const uint4*)(dbase + (size_t)r * DMODEL + (kc + 2) * 256 + c);
                if ((kc & 1) == 0) stA[it] = v; else stB[it] = v;
            }
        }

        const u16* sAc = (const u16*)sA[kc & 1];
        bf16x8 wf[2][4];
#pragma unroll
        for (int ct = 0; ct < 4; ++ct) {
            size_t ctile = (size_t)(nb * 16 + wc * 4 + ct);
            size_t ktile = (size_t)(kc * 8 + 0);
            wf[0][ct] = *(const bf16x8*)(woP + (ctile * 32 + ktile) * 512 + lane * 8);
        }
#pragma unroll
        for (int ks = 0; ks < 8; ++ks) {
            if (ks < 7) {
#pragma unroll
                for (int ct = 0; ct < 4; ++ct) {
                    size_t ctile = (size_t)(nb * 16 + wc * 4 + ct);
                    size_t ktile = (size_t)(kc * 8 + ks + 1);
                    wf[(ks + 1) & 1][ct] = *(const bf16x8*)(woP + (ctile * 32 + ktile) * 512 + lane * 8);
                }
            }
            bf16x8 afr[4];
#pragma unroll
            for (int rt = 0; rt < 4; ++rt) {
                int arow = wr * 64 + rt * 16 + (lane & 15);
                int k0 = ks * 32 + (lane >> 4) * 8;
                u32 off = ((u32)(arow * 512 + k0 * 2)) ^ ((u32)(arow & 7) << 4);
                afr[rt] = *(const bf16x8*)((const char*)sAc + off);
            }
#pragma unroll
            for (int ct = 0; ct < 4; ++ct)
#pragma unroll
                for (int rt = 0; rt < 4; ++rt)
                    acc[rt][ct] = MFMA16(afr[rt], wf[ks & 1][ct], acc[rt][ct]);
        }
    }

    // epilogue: store only (residual already folded into acc init)
#pragma unroll
    for (int rt = 0; rt < 4; ++rt)
#pragma unroll
        for (int ct = 0; ct < 4; ++ct) {
            int rbase = m0 + wr * 64 + rt * 16 + (lane >> 4) * 4;
            int col = n0 + wc * 64 + ct * 16 + (lane & 15);
#pragma unroll
            for (int q = 0; q < 4; ++q) {
                size_t o = (size_t)(rbase + q) * DMODEL + col;
                out[o] = acc[rt][ct][q];
            }
        }
}

// ---------------------------------------------------------------- launcher
extern "C" void kernel_launch(void* const* d_in, const int* in_sizes, int n_in,
                              void* d_out, int out_size, void* d_ws, size_t ws_size,
                              hipStream_t stream) {
    const float* x  = (const float*)d_in[0];
    const float* nw = (const float*)d_in[1];
    const float* Wg = (const float*)d_in[2];
    const float* Wu = (const float*)d_in[3];
    const float* Wd = (const float*)d_in[4];
    const float* Wo = (const float*)d_in[5];
    float* out = (float*)d_out;

    char* ws = (char*)d_ws;
    const size_t MB = 1u << 20;
    u16* h    = (u16*)(ws);             // 32 MB
    u16* wgP  = (u16*)(ws + 32 * MB);   //  1 MB
    u16* wuP  = (u16*)(ws + 33 * MB);   //  1 MB
    u16* wdP  = (u16*)(ws + 34 * MB);   //  1 MB
    u16* woP  = (u16*)(ws + 35 * MB);   //  2 MB
    u16* dmid = (u16*)(ws + 37 * MB);   // 32 MB  (end: 69 MB)

    k_prep<<<1280 + NTOK, 256, 0, stream>>>(Wg, Wu, Wd, Wo, x, nw,
                                            wgP, wuP, wdP, woP, h);
    k_swiglu<<<256 * NSUB, 512, 0, stream>>>(h, wgP, wuP, wdP, dmid);
    k_final<<<128 * 4, 512, 0, stream>>>(dmid, woP, x, out);
}